// Round 6
// baseline (102.806 us; speedup 1.0000x reference)
//
#include <hip/hip_runtime.h>
#include <math.h>

#pragma clang fp contract(off)

// Problem constants (fixed shapes from the reference)
#define CCH   192          // B*c = 64*3
#define HW    (512*512)    // 262144 pixels per channel
#define RNUM  8            // region_num
#define SPLIT 8            // reduction blocks per channel in pass 1

typedef float f32x4 __attribute__((ext_vector_type(4)));

// ---------------------------------------------------------------------------
// Un-contractible fp32 RN ops (HIP's __f*_rn are contractable; hipcc default
// -ffp-contract=fast-honor-pragmas fused mul+add in round 1 -> region flips).
// absmax==0.0 confirmed with these in rounds 4-5.
// ---------------------------------------------------------------------------
__device__ __forceinline__ float mul_rn(float a, float b) {
    float r; asm volatile("v_mul_f32 %0, %1, %2" : "=v"(r) : "v"(a), "v"(b)); return r;
}
__device__ __forceinline__ float add_rn(float a, float b) {
    float r; asm volatile("v_add_f32 %0, %1, %2" : "=v"(r) : "v"(a), "v"(b)); return r;
}
__device__ __forceinline__ float sub_rn(float a, float b) {
    float r; asm volatile("v_sub_f32 %0, %1, %2" : "=v"(r) : "v"(a), "v"(b)); return r;
}

// ---------------------------------------------------------------------------
// Pass 1: per-(channel, split) min/max partial reduction. float4 loads,
// LDS tree reduce. Normal (caching) loads on purpose: this pass makes x
// resident in the 256 MiB memory-side L3 for pass 2.
// ---------------------------------------------------------------------------
__global__ __launch_bounds__(256) void k_minmax(const float* __restrict__ x,
                                                float* __restrict__ ws) {
    __shared__ float smn[256], smx[256];
    const int chan = blockIdx.x / SPLIT;
    const int part = blockIdx.x % SPLIT;
    const int n4   = HW / 4 / SPLIT;  // 8192 float4 per block

    const f32x4* px = (const f32x4*)(x + (size_t)chan * HW) + (size_t)part * n4;

    float mn = INFINITY, mx = -INFINITY;
    #pragma unroll 4
    for (int i = threadIdx.x; i < n4; i += 256) {
        f32x4 v = px[i];
        mn = fminf(mn, fminf(fminf(v.x, v.y), fminf(v.z, v.w)));
        mx = fmaxf(mx, fmaxf(fmaxf(v.x, v.y), fmaxf(v.z, v.w)));
    }
    smn[threadIdx.x] = mn;
    smx[threadIdx.x] = mx;
    __syncthreads();
    for (int s = 128; s > 0; s >>= 1) {
        if (threadIdx.x < s) {
            smn[threadIdx.x] = fminf(smn[threadIdx.x], smn[threadIdx.x + s]);
            smx[threadIdx.x] = fmaxf(smx[threadIdx.x], smx[threadIdx.x + s]);
        }
        __syncthreads();
    }
    if (threadIdx.x == 0) {
        ws[(size_t)blockIdx.x * 2 + 0] = smn[0];
        ws[(size_t)blockIdx.x * 2 + 1] = smx[0];
    }
}

// ---------------------------------------------------------------------------
// Pass 2 (fused params+apply): each block recomputes its channel's params
// from the 16 partial floats (bit-identical, thread 0), broadcasts via LDS
// into registers, then per-pixel selects the region rand value via a
// register BST: 7 v_cmp + 7 v_cndmask, no per-element LDS.
//   id = count(b_i <= v)  ->  value = v<b3 ? (v<b1 ? (v<b0?r0:r1)
//                                              : (v<b2?r2:r3))
//                                     : (v<b5 ? (v<b4?r4:r5)
//                                              : (v<b6?r6:r7))
// x loads are NON-TEMPORAL: a hit should demote the line so the L3 keeps
// only the UNREAD tail of x (201 MB) resident instead of thrashing against
// the write stream. out stores are non-temporal too (no L3 allocation).
// ---------------------------------------------------------------------------
#define BLOCKS_PER_CH 16
__global__ __launch_bounds__(256) void k_apply(const float* __restrict__ x,
                                               const float* __restrict__ ws_part,
                                               const float* __restrict__ region_percentiles,
                                               const float* __restrict__ proxy_percentiles,
                                               float* __restrict__ out) {
    const int chan = blockIdx.x / BLOCKS_PER_CH;
    const int blk  = blockIdx.x % BLOCKS_PER_CH;
    const int n4   = HW / 4 / BLOCKS_PER_CH;  // 4096 float4 per block

    __shared__ float spart[2 * SPLIT];
    __shared__ float sb[RNUM - 1];
    __shared__ float srv[RNUM];

    if (threadIdx.x < 2 * SPLIT)
        spart[threadIdx.x] = ws_part[chan * 2 * SPLIT + threadIdx.x];
    __syncthreads();

    if (threadIdx.x == 0) {
        float mn = INFINITY, mx = -INFINITY;
        #pragma unroll
        for (int p = 0; p < SPLIT; ++p) {
            mn = fminf(mn, spart[2 * p + 0]);
            mx = fmaxf(mx, spart[2 * p + 1]);
        }
        const float range = sub_rn(mx, mn);

        float pos[RNUM - 1];
        #pragma unroll
        for (int i = 0; i < RNUM - 1; ++i)
            pos[i] = add_rn(mul_rn(region_percentiles[chan * (RNUM - 1) + i], range), mn);
        // insertion sort (7 elements)
        for (int i = 1; i < RNUM - 1; ++i) {
            float v = pos[i];
            int j = i - 1;
            while (j >= 0 && pos[j] > v) { pos[j + 1] = pos[j]; --j; }
            pos[j + 1] = v;
        }
        #pragma unroll
        for (int i = 0; i < RNUM - 1; ++i) sb[i] = pos[i];
        #pragma unroll
        for (int i = 0; i < RNUM; ++i) {
            const float left  = (i == 0)        ? mn : pos[i - 1];
            const float right = (i == RNUM - 1) ? add_rn(mx, 1e-6f) : pos[i];
            srv[i] = add_rn(left,
                            mul_rn(proxy_percentiles[chan * RNUM + i],
                                   sub_rn(right, left)));
        }
    }
    __syncthreads();

    // broadcast params into registers
    const float b0 = sb[0], b1 = sb[1], b2 = sb[2], b3 = sb[3];
    const float b4 = sb[4], b5 = sb[5], b6 = sb[6];
    const float r0 = srv[0], r1 = srv[1], r2 = srv[2], r3 = srv[3];
    const float r4 = srv[4], r5 = srv[5], r6 = srv[6], r7 = srv[7];

    const f32x4* px = (const f32x4*)(x   + (size_t)chan * HW) + (size_t)blk * n4;
    f32x4*       po = (f32x4*)      (out + (size_t)chan * HW) + (size_t)blk * n4;

    #pragma unroll 4
    for (int i = threadIdx.x; i < n4; i += 256) {
        const f32x4 v = __builtin_nontemporal_load(&px[i]);
        f32x4 o;
        o.x = (v.x < b3) ? ((v.x < b1) ? ((v.x < b0) ? r0 : r1)
                                       : ((v.x < b2) ? r2 : r3))
                         : ((v.x < b5) ? ((v.x < b4) ? r4 : r5)
                                       : ((v.x < b6) ? r6 : r7));
        o.y = (v.y < b3) ? ((v.y < b1) ? ((v.y < b0) ? r0 : r1)
                                       : ((v.y < b2) ? r2 : r3))
                         : ((v.y < b5) ? ((v.y < b4) ? r4 : r5)
                                       : ((v.y < b6) ? r6 : r7));
        o.z = (v.z < b3) ? ((v.z < b1) ? ((v.z < b0) ? r0 : r1)
                                       : ((v.z < b2) ? r2 : r3))
                         : ((v.z < b5) ? ((v.z < b4) ? r4 : r5)
                                       : ((v.z < b6) ? r6 : r7));
        o.w = (v.w < b3) ? ((v.w < b1) ? ((v.w < b0) ? r0 : r1)
                                       : ((v.w < b2) ? r2 : r3))
                         : ((v.w < b5) ? ((v.w < b4) ? r4 : r5)
                                       : ((v.w < b6) ? r6 : r7));
        __builtin_nontemporal_store(o, &po[i]);
    }
}

// ---------------------------------------------------------------------------
extern "C" void kernel_launch(void* const* d_in, const int* in_sizes, int n_in,
                              void* d_out, int out_size, void* d_ws, size_t ws_size,
                              hipStream_t stream) {
    const float* x  = (const float*)d_in[0];
    const float* rp = (const float*)d_in[1];  // region_percentiles, C*(R-1)
    const float* pp = (const float*)d_in[2];  // proxy_percentiles,  C*R
    // d_in[3] = region_num (hard-coded 8, matches reference constant)
    float* out = (float*)d_out;
    float* ws  = (float*)d_ws;

    k_minmax<<<CCH * SPLIT, 256, 0, stream>>>(x, ws);
    k_apply<<<CCH * BLOCKS_PER_CH, 256, 0, stream>>>(x, ws, rp, pp, out);
}

// Round 7
// 93.787 us; speedup vs baseline: 1.0962x; 1.0962x over previous
//
#include <hip/hip_runtime.h>
#include <math.h>

#pragma clang fp contract(off)

// Problem constants (fixed shapes from the reference)
#define CCH   192          // B*c = 64*3
#define HW    (512*512)    // 262144 pixels per channel
#define RNUM  8            // region_num
#define SPLIT 8            // blocks per channel, BOTH passes (same chunk map)

typedef float f32x4 __attribute__((ext_vector_type(4)));

// ---------------------------------------------------------------------------
// Un-contractible fp32 RN ops (HIP's __f*_rn are contractable; hipcc default
// -ffp-contract=fast-honor-pragmas fused mul+add in round 1 -> region flips).
// absmax==0.0 confirmed with these in rounds 4-6.
// ---------------------------------------------------------------------------
__device__ __forceinline__ float mul_rn(float a, float b) {
    float r; asm volatile("v_mul_f32 %0, %1, %2" : "=v"(r) : "v"(a), "v"(b)); return r;
}
__device__ __forceinline__ float add_rn(float a, float b) {
    float r; asm volatile("v_add_f32 %0, %1, %2" : "=v"(r) : "v"(a), "v"(b)); return r;
}
__device__ __forceinline__ float sub_rn(float a, float b) {
    float r; asm volatile("v_sub_f32 %0, %1, %2" : "=v"(r) : "v"(a), "v"(b)); return r;
}

#define N4_PER_BLOCK (HW / 4 / SPLIT)   // 8192 f32x4 per block
#define STEPS        (N4_PER_BLOCK / 256)  // 32 strided steps per thread

// ---------------------------------------------------------------------------
// Pass 1: per-(channel, split) min/max partial reduction. float4 loads,
// ASCENDING stride loop. All blocks co-resident -> at pass end, each thread-
// chunk's LATE indices are the newest lines in the L3 (sawtooth recency).
// ---------------------------------------------------------------------------
__global__ __launch_bounds__(256) void k_minmax(const float* __restrict__ x,
                                                float* __restrict__ ws) {
    __shared__ float smn[256], smx[256];
    const int chan = blockIdx.x / SPLIT;
    const int part = blockIdx.x % SPLIT;

    const f32x4* px = (const f32x4*)(x + (size_t)chan * HW) + (size_t)part * N4_PER_BLOCK;

    float mn = INFINITY, mx = -INFINITY;
    #pragma unroll 4
    for (int i = threadIdx.x; i < N4_PER_BLOCK; i += 256) {
        f32x4 v = px[i];
        mn = fminf(mn, fminf(fminf(v.x, v.y), fminf(v.z, v.w)));
        mx = fmaxf(mx, fmaxf(fmaxf(v.x, v.y), fmaxf(v.z, v.w)));
    }
    smn[threadIdx.x] = mn;
    smx[threadIdx.x] = mx;
    __syncthreads();
    for (int s = 128; s > 0; s >>= 1) {
        if (threadIdx.x < s) {
            smn[threadIdx.x] = fminf(smn[threadIdx.x], smn[threadIdx.x + s]);
            smx[threadIdx.x] = fmaxf(smx[threadIdx.x], smx[threadIdx.x + s]);
        }
        __syncthreads();
    }
    if (threadIdx.x == 0) {
        ws[(size_t)blockIdx.x * 2 + 0] = smn[0];
        ws[(size_t)blockIdx.x * 2 + 1] = smx[0];
    }
}

// ---------------------------------------------------------------------------
// Pass 2 (fused params+apply): SAME grid geometry and chunk mapping as pass 1
// (8 blocks/channel), but each thread walks its chunk in REVERSE — newest-
// recency L3 lines first. LRU evictions driven by the out-write allocations
// consume each chunk's oldest (early) lines, which we now need LAST ->
// ~half the re-read should hit L3 instead of ~none (same-order pathology).
// Per-pixel value via register BST (7 v_cmp + 7 v_cndmask, no per-elem LDS).
// NT stores keep the write stream out of L2.
// ---------------------------------------------------------------------------
__global__ __launch_bounds__(256) void k_apply(const float* __restrict__ x,
                                               const float* __restrict__ ws_part,
                                               const float* __restrict__ region_percentiles,
                                               const float* __restrict__ proxy_percentiles,
                                               float* __restrict__ out) {
    const int chan = blockIdx.x / SPLIT;
    const int blk  = blockIdx.x % SPLIT;

    __shared__ float spart[2 * SPLIT];
    __shared__ float sb[RNUM - 1];
    __shared__ float srv[RNUM];

    if (threadIdx.x < 2 * SPLIT)
        spart[threadIdx.x] = ws_part[chan * 2 * SPLIT + threadIdx.x];
    __syncthreads();

    if (threadIdx.x == 0) {
        float mn = INFINITY, mx = -INFINITY;
        #pragma unroll
        for (int p = 0; p < SPLIT; ++p) {
            mn = fminf(mn, spart[2 * p + 0]);
            mx = fmaxf(mx, spart[2 * p + 1]);
        }
        const float range = sub_rn(mx, mn);

        float pos[RNUM - 1];
        #pragma unroll
        for (int i = 0; i < RNUM - 1; ++i)
            pos[i] = add_rn(mul_rn(region_percentiles[chan * (RNUM - 1) + i], range), mn);
        // insertion sort (7 elements)
        for (int i = 1; i < RNUM - 1; ++i) {
            float v = pos[i];
            int j = i - 1;
            while (j >= 0 && pos[j] > v) { pos[j + 1] = pos[j]; --j; }
            pos[j + 1] = v;
        }
        #pragma unroll
        for (int i = 0; i < RNUM - 1; ++i) sb[i] = pos[i];
        #pragma unroll
        for (int i = 0; i < RNUM; ++i) {
            const float left  = (i == 0)        ? mn : pos[i - 1];
            const float right = (i == RNUM - 1) ? add_rn(mx, 1e-6f) : pos[i];
            srv[i] = add_rn(left,
                            mul_rn(proxy_percentiles[chan * RNUM + i],
                                   sub_rn(right, left)));
        }
    }
    __syncthreads();

    // broadcast params into registers
    const float b0 = sb[0], b1 = sb[1], b2 = sb[2], b3 = sb[3];
    const float b4 = sb[4], b5 = sb[5], b6 = sb[6];
    const float r0 = srv[0], r1 = srv[1], r2 = srv[2], r3 = srv[3];
    const float r4 = srv[4], r5 = srv[5], r6 = srv[6], r7 = srv[7];

    const f32x4* px = (const f32x4*)(x   + (size_t)chan * HW) + (size_t)blk * N4_PER_BLOCK;
    f32x4*       po = (f32x4*)      (out + (size_t)chan * HW) + (size_t)blk * N4_PER_BLOCK;

    // REVERSE walk of the exact index set pass 1 touched (newest lines first)
    #pragma unroll 4
    for (int i = (STEPS - 1) * 256 + (int)threadIdx.x; i >= 0; i -= 256) {
        const f32x4 v = px[i];
        f32x4 o;
        o.x = (v.x < b3) ? ((v.x < b1) ? ((v.x < b0) ? r0 : r1)
                                       : ((v.x < b2) ? r2 : r3))
                         : ((v.x < b5) ? ((v.x < b4) ? r4 : r5)
                                       : ((v.x < b6) ? r6 : r7));
        o.y = (v.y < b3) ? ((v.y < b1) ? ((v.y < b0) ? r0 : r1)
                                       : ((v.y < b2) ? r2 : r3))
                         : ((v.y < b5) ? ((v.y < b4) ? r4 : r5)
                                       : ((v.y < b6) ? r6 : r7));
        o.z = (v.z < b3) ? ((v.z < b1) ? ((v.z < b0) ? r0 : r1)
                                       : ((v.z < b2) ? r2 : r3))
                         : ((v.z < b5) ? ((v.z < b4) ? r4 : r5)
                                       : ((v.z < b6) ? r6 : r7));
        o.w = (v.w < b3) ? ((v.w < b1) ? ((v.w < b0) ? r0 : r1)
                                       : ((v.w < b2) ? r2 : r3))
                         : ((v.w < b5) ? ((v.w < b4) ? r4 : r5)
                                       : ((v.w < b6) ? r6 : r7));
        __builtin_nontemporal_store(o, &po[i]);
    }
}

// ---------------------------------------------------------------------------
extern "C" void kernel_launch(void* const* d_in, const int* in_sizes, int n_in,
                              void* d_out, int out_size, void* d_ws, size_t ws_size,
                              hipStream_t stream) {
    const float* x  = (const float*)d_in[0];
    const float* rp = (const float*)d_in[1];  // region_percentiles, C*(R-1)
    const float* pp = (const float*)d_in[2];  // proxy_percentiles,  C*R
    // d_in[3] = region_num (hard-coded 8, matches reference constant)
    float* out = (float*)d_out;
    float* ws  = (float*)d_ws;

    k_minmax<<<CCH * SPLIT, 256, 0, stream>>>(x, ws);
    k_apply<<<CCH * SPLIT, 256, 0, stream>>>(x, ws, rp, pp, out);
}